// Round 12
// baseline (323.394 us; speedup 1.0000x reference)
//
#include <hip/hip_runtime.h>
#include <math.h>

#define NNODES 50000
#define NEDGES 800000
#define NEG_SLOPE 0.2f
#define MPAD 50048   // 391 * 128
#define CAPW 64      // fast path: deg <= 64, one edge per lane

typedef __attribute__((ext_vector_type(8))) short short8;
typedef __attribute__((ext_vector_type(4))) float floatx4;

// bf16 helpers (RNE)
__device__ __forceinline__ unsigned short f2bf(float f) {
    union { float f; unsigned int u; } v; v.f = f;
    unsigned int r = v.u + 0x7FFFu + ((v.u >> 16) & 1u);
    return (unsigned short)(r >> 16);
}
__device__ __forceinline__ float bf2f(unsigned int s) {
    union { unsigned int u; float f; } v; v.u = s << 16; return v.f;
}
__device__ __forceinline__ float lrelu(float e) { return e > 0.f ? e : NEG_SLOPE * e; }

// ---------------------------------------------------------------------------
// prep: merged prologue (verified R7-R11).
// ---------------------------------------------------------------------------
__global__ __launch_bounds__(256) void prep(const float* __restrict__ x,
                                            const float* __restrict__ W1,
                                            const float* __restrict__ W2,
                                            const int* __restrict__ dst,
                                            unsigned short* __restrict__ xb,
                                            unsigned short* __restrict__ bfrag1,
                                            unsigned short* __restrict__ bfrag2,
                                            unsigned short* __restrict__ h1b,
                                            int* __restrict__ row_ptr) {
    int b = blockIdx.x;
    if (b < 12512) {
        long e = ((long)b * 256 + threadIdx.x) * 4;
        const long NE = (long)NNODES * 256;
        ushort4 o;
        o.x = (e + 0 < NE) ? f2bf(x[e + 0]) : 0;
        o.y = (e + 1 < NE) ? f2bf(x[e + 1]) : 0;
        o.z = (e + 2 < NE) ? f2bf(x[e + 2]) : 0;
        o.w = (e + 3 < NE) ? f2bf(x[e + 3]) : 0;
        *(ushort4*)(xb + e) = o;
    } else if (b < 12708) {
        int n = (b - 12512) * 256 + threadIdx.x;
        if (n > NNODES) return;
        int lo = 0, hi = NEDGES;
        while (lo < hi) {
            int mid = (lo + hi) >> 1;
            if (dst[mid] < n) lo = mid + 1; else hi = mid;
        }
        row_ptr[n] = lo;
    } else if (b < 12740) {
        int c = (b - 12708) * 256 + threadIdx.x;   // 8192 chunks
        int l = c & 63, kk = (c >> 6) & 7, t = c >> 9;
        int n = t * 16 + (l & 15);
        int kbase = kk * 32 + (l >> 4) * 8;
#pragma unroll
        for (int j = 0; j < 8; j++)
            bfrag1[c * 8 + j] = f2bf(W1[(kbase + j) * 256 + n]);
    } else if (b < 12746) {
        int c = (b - 12740) * 256 + threadIdx.x;   // 1536 chunks
        int l = c & 63, kk = (c >> 6) & 7, t = c >> 9;
        int n = t * 16 + (l & 15);
        int kbase = kk * 32 + (l >> 4) * 8;
#pragma unroll
        for (int j = 0; j < 8; j++)
            bfrag2[c * 8 + j] = (n < 47) ? f2bf(W2[(kbase + j) * 47 + n]) : 0;
    } else {
        int row = NNODES + (b - 12746);
        h1b[(size_t)row * 256 + threadIdx.x] = 0;
    }
}

// ---------------------------------------------------------------------------
// GEMM1 + fused logits1 — EXACT R11-verified form (gridDim.y=4, one head
// per block, acc[2][4]). R13/R14: traffic-reduction via bigger blocks is a
// dead axis. Do not re-fuse. R21 (instrumentation): launched 3x (idempotent
// pure function) — total delta / 2 = gemm1 duration.
// ---------------------------------------------------------------------------
__global__ __launch_bounds__(256) void mfma_gemm1(const unsigned short* __restrict__ xb,
                                                  const unsigned short* __restrict__ bfrag,
                                                  const float* __restrict__ al1,
                                                  const float* __restrict__ ar1,
                                                  unsigned short* __restrict__ fs1b,
                                                  float* __restrict__ el,
                                                  float* __restrict__ er) {
    const int w = threadIdx.x >> 6;
    const int l = threadIdx.x & 63;
    const int bm = blockIdx.x * 128;
    const int head = blockIdx.y;
    const int n0 = head * 64;
    const int lm = l & 15, lk = l >> 4;

    floatx4 acc[2][4];
#pragma unroll
    for (int i = 0; i < 2; i++)
#pragma unroll
        for (int j = 0; j < 4; j++) acc[i][j] = (floatx4){0.f, 0.f, 0.f, 0.f};

    const int t0 = n0 >> 4;
#pragma unroll
    for (int kk = 0; kk < 8; kk++) {
        const unsigned short* abase = xb + (size_t)(bm + w * 32 + lm) * 256 + kk * 32 + lk * 8;
        short8 a0 = *(const short8*)(abase);
        short8 a1 = *(const short8*)(abase + 16 * 256);
        const unsigned short* bbase = bfrag + ((t0 * 8 + kk) * 64 + l) * 8;
        short8 b[4];
#pragma unroll
        for (int j = 0; j < 4; j++) b[j] = *(const short8*)(bbase + j * 8 * 64 * 8);
#pragma unroll
        for (int j = 0; j < 4; j++) {
            acc[0][j] = __builtin_amdgcn_mfma_f32_16x16x32_bf16(a0, b[j], acc[0][j], 0, 0, 0);
            acc[1][j] = __builtin_amdgcn_mfma_f32_16x16x32_bf16(a1, b[j], acc[1][j], 0, 0, 0);
        }
    }
#pragma unroll
    for (int i = 0; i < 2; i++) {
        int row0 = bm + w * 32 + i * 16 + lk * 4;
#pragma unroll
        for (int r = 0; r < 4; r++) {
            int row = row0 + r;
            if (row >= NNODES) continue;
#pragma unroll
            for (int j = 0; j < 4; j++) {
                int col = n0 + j * 16 + lm;
                fs1b[(size_t)row * 256 + col] = f2bf(acc[i][j][r]);
            }
        }
    }
    float alv[4], arv[4];
#pragma unroll
    for (int j = 0; j < 4; j++) {
        alv[j] = al1[head * 64 + j * 16 + lm];
        arv[j] = ar1[head * 64 + j * 16 + lm];
    }
#pragma unroll
    for (int i = 0; i < 2; i++) {
#pragma unroll
        for (int r = 0; r < 4; r++) {
            float pe = 0.f, pr = 0.f;
#pragma unroll
            for (int j = 0; j < 4; j++) {
                float fr = bf2f(f2bf(acc[i][j][r]));
                pe += fr * alv[j];
                pr += fr * arv[j];
            }
#pragma unroll
            for (int off = 1; off < 16; off <<= 1) {
                pe += __shfl_xor(pe, off);
                pr += __shfl_xor(pr, off);
            }
            int row = bm + w * 32 + i * 16 + lk * 4 + r;
            if (lm == 0 && row < NNODES) {
                el[row * 4 + head] = pe;
                er[row * 4 + head] = pr;
            }
        }
    }
}

// ---------------------------------------------------------------------------
// GEMM2 + fused logits2 (verified R11).
// ---------------------------------------------------------------------------
__global__ __launch_bounds__(256) void mfma_gemm2(const unsigned short* __restrict__ h1b,
                                                  const unsigned short* __restrict__ bfrag,
                                                  const float* __restrict__ al2,
                                                  const float* __restrict__ ar2,
                                                  unsigned short* __restrict__ fs2b,
                                                  float* __restrict__ el,
                                                  float* __restrict__ er) {
    const int w = threadIdx.x >> 6;
    const int l = threadIdx.x & 63;
    const int bm = blockIdx.x * 128;
    const int lm = l & 15, lk = l >> 4;

    floatx4 acc[2][3];
#pragma unroll
    for (int i = 0; i < 2; i++)
#pragma unroll
        for (int j = 0; j < 3; j++) acc[i][j] = (floatx4){0.f, 0.f, 0.f, 0.f};

#pragma unroll
    for (int kk = 0; kk < 8; kk++) {
        const unsigned short* abase = h1b + (size_t)(bm + w * 32 + lm) * 256 + kk * 32 + lk * 8;
        short8 a0 = *(const short8*)(abase);
        short8 a1 = *(const short8*)(abase + 16 * 256);
        const unsigned short* bbase = bfrag + (size_t)(kk * 64 + l) * 8;
        short8 b[3];
#pragma unroll
        for (int j = 0; j < 3; j++) b[j] = *(const short8*)(bbase + j * (8 * 64 * 8));
#pragma unroll
        for (int j = 0; j < 3; j++) {
            acc[0][j] = __builtin_amdgcn_mfma_f32_16x16x32_bf16(a0, b[j], acc[0][j], 0, 0, 0);
            acc[1][j] = __builtin_amdgcn_mfma_f32_16x16x32_bf16(a1, b[j], acc[1][j], 0, 0, 0);
        }
    }
#pragma unroll
    for (int i = 0; i < 2; i++) {
        int row0 = bm + w * 32 + i * 16 + lk * 4;
#pragma unroll
        for (int r = 0; r < 4; r++) {
            int row = row0 + r;
            if (row >= NNODES) continue;
#pragma unroll
            for (int j = 0; j < 3; j++) {
                int col = j * 16 + lm;
                fs2b[(size_t)row * 48 + col] = f2bf(acc[i][j][r]);
            }
        }
    }
    float alv[3], arv[3];
#pragma unroll
    for (int j = 0; j < 3; j++) {
        int col = j * 16 + lm;
        alv[j] = (col < 47) ? al2[col] : 0.f;
        arv[j] = (col < 47) ? ar2[col] : 0.f;
    }
#pragma unroll
    for (int i = 0; i < 2; i++) {
#pragma unroll
        for (int r = 0; r < 4; r++) {
            float pe = 0.f, pr = 0.f;
#pragma unroll
            for (int j = 0; j < 3; j++) {
                float fr = bf2f(f2bf(acc[i][j][r]));
                pe += fr * alv[j];
                pr += fr * arv[j];
            }
#pragma unroll
            for (int off = 1; off < 16; off <<= 1) {
                pe += __shfl_xor(pe, off);
                pr += __shfl_xor(pr, off);
            }
            int row = bm + w * 32 + i * 16 + lk * 4 + r;
            if (lm == 0 && row < NNODES) {
                el[row] = pe;
                er[row] = pr;
            }
        }
    }
}

// Accumulate 16 channels of one edge into a[0..15].
#define EDGE_ACC(G0, G1, W)                                              \
    a[0]  += (W) * bf2f((G0).x & 0xFFFFu); a[1]  += (W) * bf2f((G0).x >> 16); \
    a[2]  += (W) * bf2f((G0).y & 0xFFFFu); a[3]  += (W) * bf2f((G0).y >> 16); \
    a[4]  += (W) * bf2f((G0).z & 0xFFFFu); a[5]  += (W) * bf2f((G0).z >> 16); \
    a[6]  += (W) * bf2f((G0).w & 0xFFFFu); a[7]  += (W) * bf2f((G0).w >> 16); \
    a[8]  += (W) * bf2f((G1).x & 0xFFFFu); a[9]  += (W) * bf2f((G1).x >> 16); \
    a[10] += (W) * bf2f((G1).y & 0xFFFFu); a[11] += (W) * bf2f((G1).y >> 16); \
    a[12] += (W) * bf2f((G1).z & 0xFFFFu); a[13] += (W) * bf2f((G1).z >> 16); \
    a[14] += (W) * bf2f((G1).w & 0xFFFFu); a[15] += (W) * bf2f((G1).w >> 16);

// ---------------------------------------------------------------------------
// Layer-1 softmax + aggregate — wave per node, R11-verified loop body,
// 128-thread blocks, single dispatch. Structural limit (~67.5us); frozen.
// ---------------------------------------------------------------------------
__global__ __launch_bounds__(128) void agg1(const int* __restrict__ row_ptr,
                                            const int* __restrict__ src,
                                            const float* __restrict__ el,
                                            const float* __restrict__ er,
                                            const unsigned short* __restrict__ fs1b,
                                            const float* __restrict__ b1,
                                            unsigned short* __restrict__ h1b) {
    __shared__ float wcache[2][CAPW * 4];
    __shared__ int   scache[2][CAPW];
    const int q = threadIdx.x >> 6;
    const int l = threadIdx.x & 63;
    const int n = blockIdx.x * 2 + q;          // 25000*2 == NNODES exactly
    const int start = row_ptr[n], end = row_ptr[n + 1];
    const int deg = end - start;

    const float4 erv = *(const float4*)(er + n * 4);
    const int g = l >> 4;        // edge group 0..3
    const int c16 = l & 15;      // channel lane: owns channels c16*16 .. +15
    const int hl = c16 >> 2;     // head of those channels
    float a[16] = {};

    if (deg <= CAPW) {
        // ---- softmax: one edge per lane, single exp per head ----
        const bool act = l < deg;
        int sv = 0;
        float e0 = -1e30f, e1 = -1e30f, e2 = -1e30f, e3 = -1e30f;
        if (act) {
            sv = src[start + l];
            float4 e4 = *(const float4*)(el + sv * 4);
            e0 = lrelu(e4.x + erv.x);
            e1 = lrelu(e4.y + erv.y);
            e2 = lrelu(e4.z + erv.z);
            e3 = lrelu(e4.w + erv.w);
        }
        float M0 = e0, M1 = e1, M2 = e2, M3 = e3;
#pragma unroll
        for (int off = 32; off > 0; off >>= 1) {
            M0 = fmaxf(M0, __shfl_xor(M0, off));
            M1 = fmaxf(M1, __shfl_xor(M1, off));
            M2 = fmaxf(M2, __shfl_xor(M2, off));
            M3 = fmaxf(M3, __shfl_xor(M3, off));
        }
        float w0 = act ? __expf(e0 - M0) : 0.f;
        float w1 = act ? __expf(e1 - M1) : 0.f;
        float w2 = act ? __expf(e2 - M2) : 0.f;
        float w3 = act ? __expf(e3 - M3) : 0.f;
        float S0 = w0, S1 = w1, S2 = w2, S3 = w3;
#pragma unroll
        for (int off = 32; off > 0; off >>= 1) {
            S0 += __shfl_xor(S0, off);
            S1 += __shfl_xor(S1, off);
            S2 += __shfl_xor(S2, off);
            S3 += __shfl_xor(S3, off);
        }
        const float rs0 = deg > 0 ? 1.f / S0 : 0.f;
        const float rs1 = deg > 0 ? 1.f / S1 : 0.f;
        const float rs2 = deg > 0 ? 1.f / S2 : 0.f;
        const float rs3 = deg > 0 ? 1.f / S3 : 0.f;
        if (act) {
            scache[q][l] = sv;
            *(float4*)(&wcache[q][l * 4]) =
                make_float4(w0 * rs0, w1 * rs1, w2 * rs2, w3 * rs3);
        }
        // ---- pass B: 4 edges in flight, 2 loads per lane per edge ----
        for (int j = g; j < deg; j += 4) {
            int svj = scache[q][j];
            float wv = wcache[q][j * 4 + hl];
            const unsigned short* p = fs1b + (size_t)svj * 256 + c16 * 16;
            uint4 g0 = *(const uint4*)(p);
            uint4 g1 = *(const uint4*)(p + 8);
            EDGE_ACC(g0, g1, wv)
        }
    } else {
        // ---- slow path (deg > 64): online phase 1, per-edge recompute ----
        float m0 = -1e30f, m1 = -1e30f, m2 = -1e30f, m3 = -1e30f;
        float s0 = 0.f, s1 = 0.f, s2 = 0.f, s3 = 0.f;
        for (int i = start + l; i < end; i += 64) {
            float4 e4 = *(const float4*)(el + src[i] * 4);
            float e;
            e = lrelu(e4.x + erv.x); { float nm = fmaxf(m0, e); s0 = s0 * __expf(m0 - nm) + __expf(e - nm); m0 = nm; }
            e = lrelu(e4.y + erv.y); { float nm = fmaxf(m1, e); s1 = s1 * __expf(m1 - nm) + __expf(e - nm); m1 = nm; }
            e = lrelu(e4.z + erv.z); { float nm = fmaxf(m2, e); s2 = s2 * __expf(m2 - nm) + __expf(e - nm); m2 = nm; }
            e = lrelu(e4.w + erv.w); { float nm = fmaxf(m3, e); s3 = s3 * __expf(m3 - nm) + __expf(e - nm); m3 = nm; }
        }
        for (int off = 32; off > 0; off >>= 1) {
            float mo, so, nm;
            mo = __shfl_xor(m0, off); so = __shfl_xor(s0, off);
            nm = fmaxf(m0, mo); s0 = s0 * __expf(m0 - nm) + so * __expf(mo - nm); m0 = nm;
            mo = __shfl_xor(m1, off); so = __shfl_xor(s1, off);
            nm = fmaxf(m1, mo); s1 = s1 * __expf(m1 - nm) + so * __expf(mo - nm); m1 = nm;
            mo = __shfl_xor(m2, off); so = __shfl_xor(s2, off);
            nm = fmaxf(m2, mo); s2 = s2 * __expf(m2 - nm) + so * __expf(mo - nm); m2 = nm;
            mo = __shfl_xor(m3, off); so = __shfl_xor(s3, off);
            nm = fmaxf(m3, mo); s3 = s3 * __expf(m3 - nm) + so * __expf(mo - nm); m3 = nm;
        }
        const float Mh  = hl == 0 ? m0 : hl == 1 ? m1 : hl == 2 ? m2 : m3;
        const float Sh  = hl == 0 ? s0 : hl == 1 ? s1 : hl == 2 ? s2 : s3;
        const float rsh = deg > 0 ? 1.f / Sh : 0.f;
        const float ervh = hl == 0 ? erv.x : hl == 1 ? erv.y : hl == 2 ? erv.z : erv.w;
        for (int j = g; j < deg; j += 4) {
            int svj = src[start + j];
            float e = lrelu(el[svj * 4 + hl] + ervh);
            float wv = __expf(e - Mh) * rsh;
            const unsigned short* p = fs1b + (size_t)svj * 256 + c16 * 16;
            uint4 g0 = *(const uint4*)(p);
            uint4 g1 = *(const uint4*)(p + 8);
            EDGE_ACC(g0, g1, wv)
        }
    }
    // cross-group reduce (4 groups)
#pragma unroll
    for (int k = 0; k < 16; k++) {
        a[k] += __shfl_xor(a[k], 16);
        a[k] += __shfl_xor(a[k], 32);
    }
    if (g == 0) {   // l < 16: write channels c16*16 .. +15
        const float* bb = b1 + c16 * 16;
        float4 b0 = *(const float4*)(bb);
        float4 b1v = *(const float4*)(bb + 4);
        float4 b2v = *(const float4*)(bb + 8);
        float4 b3v = *(const float4*)(bb + 12);
        float v[16];
        v[0]  = fmaxf(a[0]  + b0.x, 0.f); v[1]  = fmaxf(a[1]  + b0.y, 0.f);
        v[2]  = fmaxf(a[2]  + b0.z, 0.f); v[3]  = fmaxf(a[3]  + b0.w, 0.f);
        v[4]  = fmaxf(a[4]  + b1v.x, 0.f); v[5]  = fmaxf(a[5]  + b1v.y, 0.f);
        v[6]  = fmaxf(a[6]  + b1v.z, 0.f); v[7]  = fmaxf(a[7]  + b1v.w, 0.f);
        v[8]  = fmaxf(a[8]  + b2v.x, 0.f); v[9]  = fmaxf(a[9]  + b2v.y, 0.f);
        v[10] = fmaxf(a[10] + b2v.z, 0.f); v[11] = fmaxf(a[11] + b2v.w, 0.f);
        v[12] = fmaxf(a[12] + b3v.x, 0.f); v[13] = fmaxf(a[13] + b3v.y, 0.f);
        v[14] = fmaxf(a[14] + b3v.z, 0.f); v[15] = fmaxf(a[15] + b3v.w, 0.f);
        uint4 o0, o1;
        o0.x = (unsigned)f2bf(v[0])  | ((unsigned)f2bf(v[1])  << 16);
        o0.y = (unsigned)f2bf(v[2])  | ((unsigned)f2bf(v[3])  << 16);
        o0.z = (unsigned)f2bf(v[4])  | ((unsigned)f2bf(v[5])  << 16);
        o0.w = (unsigned)f2bf(v[6])  | ((unsigned)f2bf(v[7])  << 16);
        o1.x = (unsigned)f2bf(v[8])  | ((unsigned)f2bf(v[9])  << 16);
        o1.y = (unsigned)f2bf(v[10]) | ((unsigned)f2bf(v[11]) << 16);
        o1.z = (unsigned)f2bf(v[12]) | ((unsigned)f2bf(v[13]) << 16);
        o1.w = (unsigned)f2bf(v[14]) | ((unsigned)f2bf(v[15]) << 16);
        unsigned short* dstp = h1b + (size_t)n * 256 + c16 * 16;
        *(uint4*)(dstp) = o0;
        *(uint4*)(dstp + 8) = o1;
    }
}

// Accumulate 12 channels (3 uint2) of one edge into a[0..11].
#define EDGE_ACC2(U0, U1, U2, W)                                             \
    a[0]  += (W) * bf2f((U0).x & 0xFFFFu); a[1]  += (W) * bf2f((U0).x >> 16); \
    a[2]  += (W) * bf2f((U0).y & 0xFFFFu); a[3]  += (W) * bf2f((U0).y >> 16); \
    a[4]  += (W) * bf2f((U1).x & 0xFFFFu); a[5]  += (W) * bf2f((U1).x >> 16); \
    a[6]  += (W) * bf2f((U1).y & 0xFFFFu); a[7]  += (W) * bf2f((U1).y >> 16); \
    a[8]  += (W) * bf2f((U2).x & 0xFFFFu); a[9]  += (W) * bf2f((U2).x >> 16); \
    a[10] += (W) * bf2f((U2).y & 0xFFFFu); a[11] += (W) * bf2f((U2).y >> 16);

// ---------------------------------------------------------------------------
// Layer-2 softmax + aggregate — R19 verified form (gather-overlap, passed).
// ---------------------------------------------------------------------------
__global__ __launch_bounds__(128) void agg2(const int* __restrict__ row_ptr,
                                            const int* __restrict__ src,
                                            const float* __restrict__ el,
                                            const float* __restrict__ er,
                                            const unsigned short* __restrict__ fs2b,
                                            const float* __restrict__ b2,
                                            float* __restrict__ out) {
    __shared__ float wcache[2][CAPW];
    __shared__ int   scache[2][CAPW];
    const int q = threadIdx.x >> 6;
    const int l = threadIdx.x & 63;
    const int n = blockIdx.x * 2 + q;
    const int start = row_ptr[n], end = row_ptr[n + 1];
    const int deg = end - start;
    const float erv = er[n];

    const int g4 = l >> 2;   // edge group 0..15
    const int c4 = l & 3;    // channel-triple owner: channels c4*12 .. +11
    float a[12] = {};

    if (deg <= CAPW) {
        const bool act = l < deg;
        int sv = 0;
        if (act) sv = src[start + l];
        // ---- prefetch edges g4 and g4+16 (addresses need only src) ----
        const bool h0 = g4 < deg, h1 = g4 + 16 < deg;
        int sv0 = h0 ? src[start + g4] : 0;
        int sv1 = h1 ? src[start + g4 + 16] : 0;
        const unsigned short* p0 = fs2b + (size_t)sv0 * 48 + c4 * 12;
        const unsigned short* p1 = fs2b + (size_t)sv1 * 48 + c4 * 12;
        uint2 u0a = *(const uint2*)(p0);
        uint2 u0b = *(const uint2*)(p0 + 4);
        uint2 u0c = *(const uint2*)(p0 + 8);
        uint2 u1a = *(const uint2*)(p1);
        uint2 u1b = *(const uint2*)(p1 + 4);
        uint2 u1c = *(const uint2*)(p1 + 8);
        // ---- softmax (el gather latency overlaps the prefetched loads) ----
        float e = act ? lrelu(el[sv] + erv) : -1e30f;
        float M = e;
#pragma unroll
        for (int off = 32; off > 0; off >>= 1) M = fmaxf(M, __shfl_xor(M, off));
        float w = act ? __expf(e - M) : 0.f;
        float S = w;
#pragma unroll
        for (int off = 32; off > 0; off >>= 1) S += __shfl_xor(S, off);
        const float rs = deg > 0 ? 1.f / S : 0.f;
        if (act) {
            scache[q][l] = sv;
            wcache[q][l] = w * rs;
        }
        // ---- consume prefetched edges ----
        float wv0 = h0 ? wcache[q][g4] : 0.f;
        float wv1 = h1 ? wcache[q][g4 + 16] : 0.f;
        EDGE_ACC2(u0a, u0b, u0c, wv0)
        EDGE_ACC2(u1a, u1b, u1c, wv1)
        // ---- rare tail (deg > 32): wave-uniform trip count ----
        for (int base = 32; base < deg; base += 16) {
            int j = g4 + base;                 // < 64 always (base<=48, g4<=15)
            bool has = j < deg;
            int svj = has ? scache[q][j] : 0;
            float wv = has ? wcache[q][j] : 0.f;
            const unsigned short* p = fs2b + (size_t)svj * 48 + c4 * 12;
            uint2 t0 = *(const uint2*)(p);
            uint2 t1 = *(const uint2*)(p + 4);
            uint2 t2 = *(const uint2*)(p + 8);
            EDGE_ACC2(t0, t1, t2, wv)
        }
    } else {
        float m = -1e30f, s = 0.f;
        for (int i = start + l; i < end; i += 64) {
            float e = lrelu(el[src[i]] + erv);
            float nm = fmaxf(m, e);
            s = s * __expf(m - nm) + __expf(e - nm);
            m = nm;
        }
        for (int off = 32; off > 0; off >>= 1) {
            float mo = __shfl_xor(m, off), so = __shfl_xor(s, off);
            float nm = fmaxf(m, mo);
            s = s * __expf(m - nm) + so * __expf(mo - nm);
            m = nm;
        }
        const float rs = deg > 0 ? 1.f / s : 0.f;
        for (int j = g4; j < deg; j += 16) {
            int svj = src[start + j];
            float wv = __expf(lrelu(el[svj] + erv) - m) * rs;
            const unsigned short* p = fs2b + (size_t)svj * 48 + c4 * 12;
            uint2 t0 = *(const uint2*)(p);
            uint2 t1 = *(const uint2*)(p + 4);
            uint2 t2 = *(const uint2*)(p + 8);
            EDGE_ACC2(t0, t1, t2, wv)
        }
    }
    // reduce across the 16 edge groups (lanes with same c4)
#pragma unroll
    for (int k = 0; k < 12; k++) {
        a[k] += __shfl_xor(a[k], 4);
        a[k] += __shfl_xor(a[k], 8);
        a[k] += __shfl_xor(a[k], 16);
        a[k] += __shfl_xor(a[k], 32);
    }
    if (g4 == 0) {
        int ch0 = c4 * 12;
#pragma unroll
        for (int t = 0; t < 12; t++) {
            int ch = ch0 + t;
            if (ch < 47) out[(size_t)n * 47 + ch] = a[t] + b2[ch];
        }
    }
}

// ---------------------------------------------------------------------------
// Launch. Inputs: 0:x 1:W1 2:al1 3:ar1 4:b1 5:W2 6:al2 7:ar2 8:b2 9:src 10:dst
// ---------------------------------------------------------------------------
extern "C" void kernel_launch(void* const* d_in, const int* in_sizes, int n_in,
                              void* d_out, int out_size, void* d_ws, size_t ws_size,
                              hipStream_t stream) {
    const float* x   = (const float*)d_in[0];
    const float* W1  = (const float*)d_in[1];
    const float* al1 = (const float*)d_in[2];
    const float* ar1 = (const float*)d_in[3];
    const float* b1  = (const float*)d_in[4];
    const float* W2  = (const float*)d_in[5];
    const float* al2 = (const float*)d_in[6];
    const float* ar2 = (const float*)d_in[7];
    const float* b2  = (const float*)d_in[8];
    const int*   src = (const int*)d_in[9];
    const int*   dst = (const int*)d_in[10];
    float* out = (float*)d_out;

    char* ws = (char*)d_ws;
    size_t off = 0;
    auto alloc = [&](size_t bytes) {
        void* p = ws + off;
        off += (bytes + 255) & ~(size_t)255;
        return p;
    };
    int*            row_ptr = (int*)alloc((NNODES + 1) * sizeof(int));
    unsigned short* xb      = (unsigned short*)alloc((size_t)MPAD * 256 * 2);
    unsigned short* bfrag1  = (unsigned short*)alloc(16 * 8 * 64 * 8 * 2);
    unsigned short* bfrag2  = (unsigned short*)alloc(3 * 8 * 64 * 8 * 2);
    unsigned short* fs1b    = (unsigned short*)alloc((size_t)NNODES * 256 * 2);
    unsigned short* h1b     = (unsigned short*)alloc((size_t)MPAD * 256 * 2);
    unsigned short* fs2b    = (unsigned short*)alloc((size_t)NNODES * 48 * 2);
    float*          el1     = (float*)alloc((size_t)NNODES * 4 * sizeof(float));
    float*          er1     = (float*)alloc((size_t)NNODES * 4 * sizeof(float));
    float*          el2     = (float*)alloc((size_t)NNODES * sizeof(float));
    float*          er2     = (float*)alloc((size_t)NNODES * sizeof(float));
    (void)ws_size; (void)n_in; (void)in_sizes; (void)out_size;

    prep<<<12794, 256, 0, stream>>>(x, W1, W2, dst, xb, bfrag1, bfrag2, h1b, row_ptr);

    // Layer 1. R21 instrumentation: gemm1 launched 3x (pure function —
    // idempotent, bit-identical final state). (total - 262.5)/2 = gemm1 dur.
    mfma_gemm1<<<dim3(MPAD / 128, 4), 256, 0, stream>>>(xb, bfrag1, al1, ar1, fs1b, el1, er1);
    mfma_gemm1<<<dim3(MPAD / 128, 4), 256, 0, stream>>>(xb, bfrag1, al1, ar1, fs1b, el1, er1);
    mfma_gemm1<<<dim3(MPAD / 128, 4), 256, 0, stream>>>(xb, bfrag1, al1, ar1, fs1b, el1, er1);
    agg1<<<NNODES / 2, 128, 0, stream>>>(row_ptr, src, el1, er1, fs1b, b1, h1b);

    // Layer 2 (logits fused into gemm2 epilogue)
    mfma_gemm2<<<MPAD / 128, 256, 0, stream>>>(h1b, bfrag2, al2, ar2, fs2b, el2, er2);
    agg2<<<NNODES / 2, 128, 0, stream>>>(row_ptr, src, el2, er2, fs2b, b2, out);
}

// Round 13
// 261.723 us; speedup vs baseline: 1.2356x; 1.2356x over previous
//
#include <hip/hip_runtime.h>
#include <math.h>

#define NNODES 50000
#define NEDGES 800000
#define NEG_SLOPE 0.2f
#define MPAD 50048   // 391 * 128 = 1564 * 32
#define CAPW 64      // fast path: deg <= 64, one edge per lane

typedef __attribute__((ext_vector_type(8))) short short8;
typedef __attribute__((ext_vector_type(4))) float floatx4;

// bf16 helpers (RNE)
__device__ __forceinline__ unsigned short f2bf(float f) {
    union { float f; unsigned int u; } v; v.f = f;
    unsigned int r = v.u + 0x7FFFu + ((v.u >> 16) & 1u);
    return (unsigned short)(r >> 16);
}
__device__ __forceinline__ float bf2f(unsigned int s) {
    union { unsigned int u; float f; } v; v.u = s << 16; return v.f;
}
__device__ __forceinline__ float lrelu(float e) { return e > 0.f ? e : NEG_SLOPE * e; }

// ---------------------------------------------------------------------------
// prep: merged prologue. R22 CHANGE: xb written in MFMA fragment-tiled
// layout (xbt) so gemm1's A-loads are lane-coalesced. For row r, col c:
//   tile=r>>5, half=(r>>4)&1, lm=r&15, kk=c>>5, lk=(c>>3)&3, elem=c&7
//   idx = (((tile*8+kk)*2+half)*64 + lk*16+lm)*8 + elem
// x-read stays fully coalesced; write side is a static permutation
// (8B chunks, pairwise-contiguous 16B).
// ---------------------------------------------------------------------------
__global__ __launch_bounds__(256) void prep(const float* __restrict__ x,
                                            const float* __restrict__ W1,
                                            const float* __restrict__ W2,
                                            const int* __restrict__ dst,
                                            unsigned short* __restrict__ xbt,
                                            unsigned short* __restrict__ bfrag1,
                                            unsigned short* __restrict__ bfrag2,
                                            unsigned short* __restrict__ h1b,
                                            int* __restrict__ row_ptr) {
    int b = blockIdx.x;
    if (b < 12512) {
        long e = ((long)b * 256 + threadIdx.x) * 4;
        const long NE = (long)NNODES * 256;
        ushort4 o;
        o.x = (e + 0 < NE) ? f2bf(x[e + 0]) : 0;
        o.y = (e + 1 < NE) ? f2bf(x[e + 1]) : 0;
        o.z = (e + 2 < NE) ? f2bf(x[e + 2]) : 0;
        o.w = (e + 3 < NE) ? f2bf(x[e + 3]) : 0;
        int row = (int)(e >> 8);          // e/256
        int c   = (int)(e & 255);         // same row for all 4 elems (c%4==0)
        int tile = row >> 5, half = (row >> 4) & 1, lm = row & 15;
        int kk = c >> 5, lk = (c >> 3) & 3, elem = c & 7;
        size_t idx = (((size_t)(tile * 8 + kk) * 2 + half) * 64 + (lk * 16 + lm)) * 8 + elem;
        *(ushort4*)(xbt + idx) = o;
    } else if (b < 12708) {
        int n = (b - 12512) * 256 + threadIdx.x;
        if (n > NNODES) return;
        int lo = 0, hi = NEDGES;
        while (lo < hi) {
            int mid = (lo + hi) >> 1;
            if (dst[mid] < n) lo = mid + 1; else hi = mid;
        }
        row_ptr[n] = lo;
    } else if (b < 12740) {
        int c = (b - 12708) * 256 + threadIdx.x;   // 8192 chunks
        int l = c & 63, kk = (c >> 6) & 7, t = c >> 9;
        int n = t * 16 + (l & 15);
        int kbase = kk * 32 + (l >> 4) * 8;
#pragma unroll
        for (int j = 0; j < 8; j++)
            bfrag1[c * 8 + j] = f2bf(W1[(kbase + j) * 256 + n]);
    } else if (b < 12746) {
        int c = (b - 12740) * 256 + threadIdx.x;   // 1536 chunks
        int l = c & 63, kk = (c >> 6) & 7, t = c >> 9;
        int n = t * 16 + (l & 15);
        int kbase = kk * 32 + (l >> 4) * 8;
#pragma unroll
        for (int j = 0; j < 8; j++)
            bfrag2[c * 8 + j] = (n < 47) ? f2bf(W2[(kbase + j) * 47 + n]) : 0;
    } else {
        int row = NNODES + (b - 12746);
        h1b[(size_t)row * 256 + threadIdx.x] = 0;
    }
}

// ---------------------------------------------------------------------------
// GEMM1 + fused logits1 — R11 grid/acc structure (gridDim.y=4, verified).
// R22 CHANGE: A read from fragment-tiled xbt — fully coalesced (1KB/instr,
// was 16 transactions/instr). tile = blockIdx.x*4 + w; a0=half0, a1=half1.
// Bit-identical math; only addresses changed.
// ---------------------------------------------------------------------------
__global__ __launch_bounds__(256) void mfma_gemm1(const unsigned short* __restrict__ xbt,
                                                  const unsigned short* __restrict__ bfrag,
                                                  const float* __restrict__ al1,
                                                  const float* __restrict__ ar1,
                                                  unsigned short* __restrict__ fs1b,
                                                  float* __restrict__ el,
                                                  float* __restrict__ er) {
    const int w = threadIdx.x >> 6;
    const int l = threadIdx.x & 63;
    const int bm = blockIdx.x * 128;
    const int head = blockIdx.y;
    const int n0 = head * 64;
    const int lm = l & 15, lk = l >> 4;
    const int tile = blockIdx.x * 4 + w;       // 32-row tile index

    floatx4 acc[2][4];
#pragma unroll
    for (int i = 0; i < 2; i++)
#pragma unroll
        for (int j = 0; j < 4; j++) acc[i][j] = (floatx4){0.f, 0.f, 0.f, 0.f};

    const int t0 = n0 >> 4;
#pragma unroll
    for (int kk = 0; kk < 8; kk++) {
        const unsigned short* abase =
            xbt + ((size_t)(tile * 8 + kk) * 2) * 512 + (size_t)l * 8;
        short8 a0 = *(const short8*)(abase);          // half 0: rows tile*32+lm
        short8 a1 = *(const short8*)(abase + 512);    // half 1: rows +16
        const unsigned short* bbase = bfrag + ((t0 * 8 + kk) * 64 + l) * 8;
        short8 b[4];
#pragma unroll
        for (int j = 0; j < 4; j++) b[j] = *(const short8*)(bbase + j * 8 * 64 * 8);
#pragma unroll
        for (int j = 0; j < 4; j++) {
            acc[0][j] = __builtin_amdgcn_mfma_f32_16x16x32_bf16(a0, b[j], acc[0][j], 0, 0, 0);
            acc[1][j] = __builtin_amdgcn_mfma_f32_16x16x32_bf16(a1, b[j], acc[1][j], 0, 0, 0);
        }
    }
#pragma unroll
    for (int i = 0; i < 2; i++) {
        int row0 = bm + w * 32 + i * 16 + lk * 4;
#pragma unroll
        for (int r = 0; r < 4; r++) {
            int row = row0 + r;
            if (row >= NNODES) continue;
#pragma unroll
            for (int j = 0; j < 4; j++) {
                int col = n0 + j * 16 + lm;
                fs1b[(size_t)row * 256 + col] = f2bf(acc[i][j][r]);
            }
        }
    }
    float alv[4], arv[4];
#pragma unroll
    for (int j = 0; j < 4; j++) {
        alv[j] = al1[head * 64 + j * 16 + lm];
        arv[j] = ar1[head * 64 + j * 16 + lm];
    }
#pragma unroll
    for (int i = 0; i < 2; i++) {
#pragma unroll
        for (int r = 0; r < 4; r++) {
            float pe = 0.f, pr = 0.f;
#pragma unroll
            for (int j = 0; j < 4; j++) {
                float fr = bf2f(f2bf(acc[i][j][r]));
                pe += fr * alv[j];
                pr += fr * arv[j];
            }
#pragma unroll
            for (int off = 1; off < 16; off <<= 1) {
                pe += __shfl_xor(pe, off);
                pr += __shfl_xor(pr, off);
            }
            int row = bm + w * 32 + i * 16 + lk * 4 + r;
            if (lm == 0 && row < NNODES) {
                el[row * 4 + head] = pe;
                er[row * 4 + head] = pr;
            }
        }
    }
}

// ---------------------------------------------------------------------------
// GEMM2 + fused logits2 (verified R11; h1b stays row-major for agg1 writes).
// ---------------------------------------------------------------------------
__global__ __launch_bounds__(256) void mfma_gemm2(const unsigned short* __restrict__ h1b,
                                                  const unsigned short* __restrict__ bfrag,
                                                  const float* __restrict__ al2,
                                                  const float* __restrict__ ar2,
                                                  unsigned short* __restrict__ fs2b,
                                                  float* __restrict__ el,
                                                  float* __restrict__ er) {
    const int w = threadIdx.x >> 6;
    const int l = threadIdx.x & 63;
    const int bm = blockIdx.x * 128;
    const int lm = l & 15, lk = l >> 4;

    floatx4 acc[2][3];
#pragma unroll
    for (int i = 0; i < 2; i++)
#pragma unroll
        for (int j = 0; j < 3; j++) acc[i][j] = (floatx4){0.f, 0.f, 0.f, 0.f};

#pragma unroll
    for (int kk = 0; kk < 8; kk++) {
        const unsigned short* abase = h1b + (size_t)(bm + w * 32 + lm) * 256 + kk * 32 + lk * 8;
        short8 a0 = *(const short8*)(abase);
        short8 a1 = *(const short8*)(abase + 16 * 256);
        const unsigned short* bbase = bfrag + (size_t)(kk * 64 + l) * 8;
        short8 b[3];
#pragma unroll
        for (int j = 0; j < 3; j++) b[j] = *(const short8*)(bbase + j * (8 * 64 * 8));
#pragma unroll
        for (int j = 0; j < 3; j++) {
            acc[0][j] = __builtin_amdgcn_mfma_f32_16x16x32_bf16(a0, b[j], acc[0][j], 0, 0, 0);
            acc[1][j] = __builtin_amdgcn_mfma_f32_16x16x32_bf16(a1, b[j], acc[1][j], 0, 0, 0);
        }
    }
#pragma unroll
    for (int i = 0; i < 2; i++) {
        int row0 = bm + w * 32 + i * 16 + lk * 4;
#pragma unroll
        for (int r = 0; r < 4; r++) {
            int row = row0 + r;
            if (row >= NNODES) continue;
#pragma unroll
            for (int j = 0; j < 3; j++) {
                int col = j * 16 + lm;
                fs2b[(size_t)row * 48 + col] = f2bf(acc[i][j][r]);
            }
        }
    }
    float alv[3], arv[3];
#pragma unroll
    for (int j = 0; j < 3; j++) {
        int col = j * 16 + lm;
        alv[j] = (col < 47) ? al2[col] : 0.f;
        arv[j] = (col < 47) ? ar2[col] : 0.f;
    }
#pragma unroll
    for (int i = 0; i < 2; i++) {
#pragma unroll
        for (int r = 0; r < 4; r++) {
            float pe = 0.f, pr = 0.f;
#pragma unroll
            for (int j = 0; j < 3; j++) {
                float fr = bf2f(f2bf(acc[i][j][r]));
                pe += fr * alv[j];
                pr += fr * arv[j];
            }
#pragma unroll
            for (int off = 1; off < 16; off <<= 1) {
                pe += __shfl_xor(pe, off);
                pr += __shfl_xor(pr, off);
            }
            int row = bm + w * 32 + i * 16 + lk * 4 + r;
            if (lm == 0 && row < NNODES) {
                el[row] = pe;
                er[row] = pr;
            }
        }
    }
}

// Accumulate 16 channels of one edge into a[0..15].
#define EDGE_ACC(G0, G1, W)                                              \
    a[0]  += (W) * bf2f((G0).x & 0xFFFFu); a[1]  += (W) * bf2f((G0).x >> 16); \
    a[2]  += (W) * bf2f((G0).y & 0xFFFFu); a[3]  += (W) * bf2f((G0).y >> 16); \
    a[4]  += (W) * bf2f((G0).z & 0xFFFFu); a[5]  += (W) * bf2f((G0).z >> 16); \
    a[6]  += (W) * bf2f((G0).w & 0xFFFFu); a[7]  += (W) * bf2f((G0).w >> 16); \
    a[8]  += (W) * bf2f((G1).x & 0xFFFFu); a[9]  += (W) * bf2f((G1).x >> 16); \
    a[10] += (W) * bf2f((G1).y & 0xFFFFu); a[11] += (W) * bf2f((G1).y >> 16); \
    a[12] += (W) * bf2f((G1).z & 0xFFFFu); a[13] += (W) * bf2f((G1).z >> 16); \
    a[14] += (W) * bf2f((G1).w & 0xFFFFu); a[15] += (W) * bf2f((G1).w >> 16);

// ---------------------------------------------------------------------------
// Layer-1 softmax + aggregate — wave per node, R11-verified loop body,
// 128-thread blocks, single dispatch. Structural limit (~67.5us); frozen.
// ---------------------------------------------------------------------------
__global__ __launch_bounds__(128) void agg1(const int* __restrict__ row_ptr,
                                            const int* __restrict__ src,
                                            const float* __restrict__ el,
                                            const float* __restrict__ er,
                                            const unsigned short* __restrict__ fs1b,
                                            const float* __restrict__ b1,
                                            unsigned short* __restrict__ h1b) {
    __shared__ float wcache[2][CAPW * 4];
    __shared__ int   scache[2][CAPW];
    const int q = threadIdx.x >> 6;
    const int l = threadIdx.x & 63;
    const int n = blockIdx.x * 2 + q;          // 25000*2 == NNODES exactly
    const int start = row_ptr[n], end = row_ptr[n + 1];
    const int deg = end - start;

    const float4 erv = *(const float4*)(er + n * 4);
    const int g = l >> 4;        // edge group 0..3
    const int c16 = l & 15;      // channel lane: owns channels c16*16 .. +15
    const int hl = c16 >> 2;     // head of those channels
    float a[16] = {};

    if (deg <= CAPW) {
        // ---- softmax: one edge per lane, single exp per head ----
        const bool act = l < deg;
        int sv = 0;
        float e0 = -1e30f, e1 = -1e30f, e2 = -1e30f, e3 = -1e30f;
        if (act) {
            sv = src[start + l];
            float4 e4 = *(const float4*)(el + sv * 4);
            e0 = lrelu(e4.x + erv.x);
            e1 = lrelu(e4.y + erv.y);
            e2 = lrelu(e4.z + erv.z);
            e3 = lrelu(e4.w + erv.w);
        }
        float M0 = e0, M1 = e1, M2 = e2, M3 = e3;
#pragma unroll
        for (int off = 32; off > 0; off >>= 1) {
            M0 = fmaxf(M0, __shfl_xor(M0, off));
            M1 = fmaxf(M1, __shfl_xor(M1, off));
            M2 = fmaxf(M2, __shfl_xor(M2, off));
            M3 = fmaxf(M3, __shfl_xor(M3, off));
        }
        float w0 = act ? __expf(e0 - M0) : 0.f;
        float w1 = act ? __expf(e1 - M1) : 0.f;
        float w2 = act ? __expf(e2 - M2) : 0.f;
        float w3 = act ? __expf(e3 - M3) : 0.f;
        float S0 = w0, S1 = w1, S2 = w2, S3 = w3;
#pragma unroll
        for (int off = 32; off > 0; off >>= 1) {
            S0 += __shfl_xor(S0, off);
            S1 += __shfl_xor(S1, off);
            S2 += __shfl_xor(S2, off);
            S3 += __shfl_xor(S3, off);
        }
        const float rs0 = deg > 0 ? 1.f / S0 : 0.f;
        const float rs1 = deg > 0 ? 1.f / S1 : 0.f;
        const float rs2 = deg > 0 ? 1.f / S2 : 0.f;
        const float rs3 = deg > 0 ? 1.f / S3 : 0.f;
        if (act) {
            scache[q][l] = sv;
            *(float4*)(&wcache[q][l * 4]) =
                make_float4(w0 * rs0, w1 * rs1, w2 * rs2, w3 * rs3);
        }
        // ---- pass B: 4 edges in flight, 2 loads per lane per edge ----
        for (int j = g; j < deg; j += 4) {
            int svj = scache[q][j];
            float wv = wcache[q][j * 4 + hl];
            const unsigned short* p = fs1b + (size_t)svj * 256 + c16 * 16;
            uint4 g0 = *(const uint4*)(p);
            uint4 g1 = *(const uint4*)(p + 8);
            EDGE_ACC(g0, g1, wv)
        }
    } else {
        // ---- slow path (deg > 64): online phase 1, per-edge recompute ----
        float m0 = -1e30f, m1 = -1e30f, m2 = -1e30f, m3 = -1e30f;
        float s0 = 0.f, s1 = 0.f, s2 = 0.f, s3 = 0.f;
        for (int i = start + l; i < end; i += 64) {
            float4 e4 = *(const float4*)(el + src[i] * 4);
            float e;
            e = lrelu(e4.x + erv.x); { float nm = fmaxf(m0, e); s0 = s0 * __expf(m0 - nm) + __expf(e - nm); m0 = nm; }
            e = lrelu(e4.y + erv.y); { float nm = fmaxf(m1, e); s1 = s1 * __expf(m1 - nm) + __expf(e - nm); m1 = nm; }
            e = lrelu(e4.z + erv.z); { float nm = fmaxf(m2, e); s2 = s2 * __expf(m2 - nm) + __expf(e - nm); m2 = nm; }
            e = lrelu(e4.w + erv.w); { float nm = fmaxf(m3, e); s3 = s3 * __expf(m3 - nm) + __expf(e - nm); m3 = nm; }
        }
        for (int off = 32; off > 0; off >>= 1) {
            float mo, so, nm;
            mo = __shfl_xor(m0, off); so = __shfl_xor(s0, off);
            nm = fmaxf(m0, mo); s0 = s0 * __expf(m0 - nm) + so * __expf(mo - nm); m0 = nm;
            mo = __shfl_xor(m1, off); so = __shfl_xor(s1, off);
            nm = fmaxf(m1, mo); s1 = s1 * __expf(m1 - nm) + so * __expf(mo - nm); m1 = nm;
            mo = __shfl_xor(m2, off); so = __shfl_xor(s2, off);
            nm = fmaxf(m2, mo); s2 = s2 * __expf(m2 - nm) + so * __expf(mo - nm); m2 = nm;
            mo = __shfl_xor(m3, off); so = __shfl_xor(s3, off);
            nm = fmaxf(m3, mo); s3 = s3 * __expf(m3 - nm) + so * __expf(mo - nm); m3 = nm;
        }
        const float Mh  = hl == 0 ? m0 : hl == 1 ? m1 : hl == 2 ? m2 : m3;
        const float Sh  = hl == 0 ? s0 : hl == 1 ? s1 : hl == 2 ? s2 : s3;
        const float rsh = deg > 0 ? 1.f / Sh : 0.f;
        const float ervh = hl == 0 ? erv.x : hl == 1 ? erv.y : hl == 2 ? erv.z : erv.w;
        for (int j = g; j < deg; j += 4) {
            int svj = src[start + j];
            float e = lrelu(el[svj * 4 + hl] + ervh);
            float wv = __expf(e - Mh) * rsh;
            const unsigned short* p = fs1b + (size_t)svj * 256 + c16 * 16;
            uint4 g0 = *(const uint4*)(p);
            uint4 g1 = *(const uint4*)(p + 8);
            EDGE_ACC(g0, g1, wv)
        }
    }
    // cross-group reduce (4 groups)
#pragma unroll
    for (int k = 0; k < 16; k++) {
        a[k] += __shfl_xor(a[k], 16);
        a[k] += __shfl_xor(a[k], 32);
    }
    if (g == 0) {   // l < 16: write channels c16*16 .. +15
        const float* bb = b1 + c16 * 16;
        float4 b0 = *(const float4*)(bb);
        float4 b1v = *(const float4*)(bb + 4);
        float4 b2v = *(const float4*)(bb + 8);
        float4 b3v = *(const float4*)(bb + 12);
        float v[16];
        v[0]  = fmaxf(a[0]  + b0.x, 0.f); v[1]  = fmaxf(a[1]  + b0.y, 0.f);
        v[2]  = fmaxf(a[2]  + b0.z, 0.f); v[3]  = fmaxf(a[3]  + b0.w, 0.f);
        v[4]  = fmaxf(a[4]  + b1v.x, 0.f); v[5]  = fmaxf(a[5]  + b1v.y, 0.f);
        v[6]  = fmaxf(a[6]  + b1v.z, 0.f); v[7]  = fmaxf(a[7]  + b1v.w, 0.f);
        v[8]  = fmaxf(a[8]  + b2v.x, 0.f); v[9]  = fmaxf(a[9]  + b2v.y, 0.f);
        v[10] = fmaxf(a[10] + b2v.z, 0.f); v[11] = fmaxf(a[11] + b2v.w, 0.f);
        v[12] = fmaxf(a[12] + b3v.x, 0.f); v[13] = fmaxf(a[13] + b3v.y, 0.f);
        v[14] = fmaxf(a[14] + b3v.z, 0.f); v[15] = fmaxf(a[15] + b3v.w, 0.f);
        uint4 o0, o1;
        o0.x = (unsigned)f2bf(v[0])  | ((unsigned)f2bf(v[1])  << 16);
        o0.y = (unsigned)f2bf(v[2])  | ((unsigned)f2bf(v[3])  << 16);
        o0.z = (unsigned)f2bf(v[4])  | ((unsigned)f2bf(v[5])  << 16);
        o0.w = (unsigned)f2bf(v[6])  | ((unsigned)f2bf(v[7])  << 16);
        o1.x = (unsigned)f2bf(v[8])  | ((unsigned)f2bf(v[9])  << 16);
        o1.y = (unsigned)f2bf(v[10]) | ((unsigned)f2bf(v[11]) << 16);
        o1.z = (unsigned)f2bf(v[12]) | ((unsigned)f2bf(v[13]) << 16);
        o1.w = (unsigned)f2bf(v[14]) | ((unsigned)f2bf(v[15]) << 16);
        unsigned short* dstp = h1b + (size_t)n * 256 + c16 * 16;
        *(uint4*)(dstp) = o0;
        *(uint4*)(dstp + 8) = o1;
    }
}

// Accumulate 12 channels (3 uint2) of one edge into a[0..11].
#define EDGE_ACC2(U0, U1, U2, W)                                             \
    a[0]  += (W) * bf2f((U0).x & 0xFFFFu); a[1]  += (W) * bf2f((U0).x >> 16); \
    a[2]  += (W) * bf2f((U0).y & 0xFFFFu); a[3]  += (W) * bf2f((U0).y >> 16); \
    a[4]  += (W) * bf2f((U1).x & 0xFFFFu); a[5]  += (W) * bf2f((U1).x >> 16); \
    a[6]  += (W) * bf2f((U1).y & 0xFFFFu); a[7]  += (W) * bf2f((U1).y >> 16); \
    a[8]  += (W) * bf2f((U2).x & 0xFFFFu); a[9]  += (W) * bf2f((U2).x >> 16); \
    a[10] += (W) * bf2f((U2).y & 0xFFFFu); a[11] += (W) * bf2f((U2).y >> 16);

// ---------------------------------------------------------------------------
// Layer-2 softmax + aggregate — R19 verified form (gather-overlap, passed).
// ---------------------------------------------------------------------------
__global__ __launch_bounds__(128) void agg2(const int* __restrict__ row_ptr,
                                            const int* __restrict__ src,
                                            const float* __restrict__ el,
                                            const float* __restrict__ er,
                                            const unsigned short* __restrict__ fs2b,
                                            const float* __restrict__ b2,
                                            float* __restrict__ out) {
    __shared__ float wcache[2][CAPW];
    __shared__ int   scache[2][CAPW];
    const int q = threadIdx.x >> 6;
    const int l = threadIdx.x & 63;
    const int n = blockIdx.x * 2 + q;
    const int start = row_ptr[n], end = row_ptr[n + 1];
    const int deg = end - start;
    const float erv = er[n];

    const int g4 = l >> 2;   // edge group 0..15
    const int c4 = l & 3;    // channel-triple owner: channels c4*12 .. +11
    float a[12] = {};

    if (deg <= CAPW) {
        const bool act = l < deg;
        int sv = 0;
        if (act) sv = src[start + l];
        // ---- prefetch edges g4 and g4+16 (addresses need only src) ----
        const bool h0 = g4 < deg, h1 = g4 + 16 < deg;
        int sv0 = h0 ? src[start + g4] : 0;
        int sv1 = h1 ? src[start + g4 + 16] : 0;
        const unsigned short* p0 = fs2b + (size_t)sv0 * 48 + c4 * 12;
        const unsigned short* p1 = fs2b + (size_t)sv1 * 48 + c4 * 12;
        uint2 u0a = *(const uint2*)(p0);
        uint2 u0b = *(const uint2*)(p0 + 4);
        uint2 u0c = *(const uint2*)(p0 + 8);
        uint2 u1a = *(const uint2*)(p1);
        uint2 u1b = *(const uint2*)(p1 + 4);
        uint2 u1c = *(const uint2*)(p1 + 8);
        // ---- softmax (el gather latency overlaps the prefetched loads) ----
        float e = act ? lrelu(el[sv] + erv) : -1e30f;
        float M = e;
#pragma unroll
        for (int off = 32; off > 0; off >>= 1) M = fmaxf(M, __shfl_xor(M, off));
        float w = act ? __expf(e - M) : 0.f;
        float S = w;
#pragma unroll
        for (int off = 32; off > 0; off >>= 1) S += __shfl_xor(S, off);
        const float rs = deg > 0 ? 1.f / S : 0.f;
        if (act) {
            scache[q][l] = sv;
            wcache[q][l] = w * rs;
        }
        // ---- consume prefetched edges ----
        float wv0 = h0 ? wcache[q][g4] : 0.f;
        float wv1 = h1 ? wcache[q][g4 + 16] : 0.f;
        EDGE_ACC2(u0a, u0b, u0c, wv0)
        EDGE_ACC2(u1a, u1b, u1c, wv1)
        // ---- rare tail (deg > 32): wave-uniform trip count ----
        for (int base = 32; base < deg; base += 16) {
            int j = g4 + base;                 // < 64 always (base<=48, g4<=15)
            bool has = j < deg;
            int svj = has ? scache[q][j] : 0;
            float wv = has ? wcache[q][j] : 0.f;
            const unsigned short* p = fs2b + (size_t)svj * 48 + c4 * 12;
            uint2 t0 = *(const uint2*)(p);
            uint2 t1 = *(const uint2*)(p + 4);
            uint2 t2 = *(const uint2*)(p + 8);
            EDGE_ACC2(t0, t1, t2, wv)
        }
    } else {
        float m = -1e30f, s = 0.f;
        for (int i = start + l; i < end; i += 64) {
            float e = lrelu(el[src[i]] + erv);
            float nm = fmaxf(m, e);
            s = s * __expf(m - nm) + __expf(e - nm);
            m = nm;
        }
        for (int off = 32; off > 0; off >>= 1) {
            float mo = __shfl_xor(m, off), so = __shfl_xor(s, off);
            float nm = fmaxf(m, mo);
            s = s * __expf(m - nm) + so * __expf(mo - nm);
            m = nm;
        }
        const float rs = deg > 0 ? 1.f / s : 0.f;
        for (int j = g4; j < deg; j += 16) {
            int svj = src[start + j];
            float wv = __expf(lrelu(el[svj] + erv) - m) * rs;
            const unsigned short* p = fs2b + (size_t)svj * 48 + c4 * 12;
            uint2 t0 = *(const uint2*)(p);
            uint2 t1 = *(const uint2*)(p + 4);
            uint2 t2 = *(const uint2*)(p + 8);
            EDGE_ACC2(t0, t1, t2, wv)
        }
    }
    // reduce across the 16 edge groups (lanes with same c4)
#pragma unroll
    for (int k = 0; k < 12; k++) {
        a[k] += __shfl_xor(a[k], 4);
        a[k] += __shfl_xor(a[k], 8);
        a[k] += __shfl_xor(a[k], 16);
        a[k] += __shfl_xor(a[k], 32);
    }
    if (g4 == 0) {
        int ch0 = c4 * 12;
#pragma unroll
        for (int t = 0; t < 12; t++) {
            int ch = ch0 + t;
            if (ch < 47) out[(size_t)n * 47 + ch] = a[t] + b2[ch];
        }
    }
}

// ---------------------------------------------------------------------------
// Launch. Inputs: 0:x 1:W1 2:al1 3:ar1 4:b1 5:W2 6:al2 7:ar2 8:b2 9:src 10:dst
// ---------------------------------------------------------------------------
extern "C" void kernel_launch(void* const* d_in, const int* in_sizes, int n_in,
                              void* d_out, int out_size, void* d_ws, size_t ws_size,
                              hipStream_t stream) {
    const float* x   = (const float*)d_in[0];
    const float* W1  = (const float*)d_in[1];
    const float* al1 = (const float*)d_in[2];
    const float* ar1 = (const float*)d_in[3];
    const float* b1  = (const float*)d_in[4];
    const float* W2  = (const float*)d_in[5];
    const float* al2 = (const float*)d_in[6];
    const float* ar2 = (const float*)d_in[7];
    const float* b2  = (const float*)d_in[8];
    const int*   src = (const int*)d_in[9];
    const int*   dst = (const int*)d_in[10];
    float* out = (float*)d_out;

    char* ws = (char*)d_ws;
    size_t off = 0;
    auto alloc = [&](size_t bytes) {
        void* p = ws + off;
        off += (bytes + 255) & ~(size_t)255;
        return p;
    };
    int*            row_ptr = (int*)alloc((NNODES + 1) * sizeof(int));
    unsigned short* xbt     = (unsigned short*)alloc((size_t)MPAD * 256 * 2);
    unsigned short* bfrag1  = (unsigned short*)alloc(16 * 8 * 64 * 8 * 2);
    unsigned short* bfrag2  = (unsigned short*)alloc(3 * 8 * 64 * 8 * 2);
    unsigned short* fs1b    = (unsigned short*)alloc((size_t)NNODES * 256 * 2);
    unsigned short* h1b     = (unsigned short*)alloc((size_t)MPAD * 256 * 2);
    unsigned short* fs2b    = (unsigned short*)alloc((size_t)NNODES * 48 * 2);
    float*          el1     = (float*)alloc((size_t)NNODES * 4 * sizeof(float));
    float*          er1     = (float*)alloc((size_t)NNODES * 4 * sizeof(float));
    float*          el2     = (float*)alloc((size_t)NNODES * sizeof(float));
    float*          er2     = (float*)alloc((size_t)NNODES * sizeof(float));
    (void)ws_size; (void)n_in; (void)in_sizes; (void)out_size;

    prep<<<12794, 256, 0, stream>>>(x, W1, W2, dst, xbt, bfrag1, bfrag2, h1b, row_ptr);

    // Layer 1 (logits fused into gemm1 epilogue; fragment-tiled A)
    mfma_gemm1<<<dim3(MPAD / 128, 4), 256, 0, stream>>>(xbt, bfrag1, al1, ar1, fs1b, el1, er1);
    agg1<<<NNODES / 2, 128, 0, stream>>>(row_ptr, src, el1, er1, fs1b, b1, h1b);

    // Layer 2 (logits fused into gemm2 epilogue)
    mfma_gemm2<<<MPAD / 128, 256, 0, stream>>>(h1b, bfrag2, al2, ar2, fs2b, el2, er2);
    agg2<<<NNODES / 2, 128, 0, stream>>>(row_ptr, src, el2, er2, fs2b, b2, out);
}